// Round 1
// baseline (4555.075 us; speedup 1.0000x reference)
//
#include <hip/hip_runtime.h>

#define NTOK 577
#define BATCH 4
#define HEADS 12
#define LAYERS 12
#define CDIM 768
#define DHEAD 64
#define SSEL 57
#define KEEP 58
#define MROWS (BATCH * NTOK)  // 2308

// ---------------------------------------------------------------------------
// init: v = e0 per batch (rollout left-vector), zero selpos/union masks
// ---------------------------------------------------------------------------
__global__ void init_kernel(float* v0, int* selpos, int* unionmask) {
  int i = blockIdx.x * 256 + threadIdx.x;
  if (i < BATCH * NTOK) {
    v0[i] = ((i % NTOK) == 0) ? 1.f : 0.f;
    selpos[i] = 0;
  }
  if (i < NTOK) unionmask[i] = 0;
}

// ---------------------------------------------------------------------------
// fuse_select: one block per (b,i) row of one layer.
//   fused = mean over 12 heads; radix-select 58th largest (exact, positive
//   floats -> uint order); kept set = top58 ∪ {col 0}; write normalized row
//   A[i][j] = (kept*fused + (j==i)) / (sum_kept + 1).   (0.5 factors cancel)
// ---------------------------------------------------------------------------
__global__ __launch_bounds__(256) void fuse_select(const float* __restrict__ attn_l,
                                                   float* __restrict__ Amat) {
  const int b = blockIdx.x / NTOK;
  const int i = blockIdx.x % NTOK;
  const int tid = threadIdx.x;
  __shared__ float row[NTOK];
  __shared__ unsigned hist[256];
  __shared__ unsigned sh_prefix;
  __shared__ int sh_k;
  __shared__ float sred[4];
  __shared__ float sh_inv;

  const float* base = attn_l + ((size_t)b * HEADS) * NTOK * NTOK + (size_t)i * NTOK;
  for (int j = tid; j < NTOK; j += 256) {
    float s = 0.f;
#pragma unroll
    for (int h = 0; h < HEADS; ++h) s += base[(size_t)h * NTOK * NTOK + j];
    row[j] = s / 12.f;  // true division to track reference mean closely
  }
  if (tid == 0) { sh_prefix = 0u; sh_k = KEEP; }
  __syncthreads();

  // MSB-first radix select of the KEEP-th largest value
  for (int pass = 0; pass < 4; ++pass) {
    const int shift = 24 - pass * 8;
    hist[tid] = 0u;
    __syncthreads();
    const unsigned pmask = (pass == 0) ? 0u : (0xFFFFFFFFu << (shift + 8));
    const unsigned pref = sh_prefix;
    for (int j = tid; j < NTOK; j += 256) {
      unsigned ub = __float_as_uint(row[j]);
      if ((ub & pmask) == pref) atomicAdd(&hist[(ub >> shift) & 255u], 1u);
    }
    __syncthreads();
    if (tid == 0) {
      int kk = sh_k;
      int c = 0, bin = 255;
      for (; bin >= 0; --bin) { c += (int)hist[bin]; if (c >= kk) break; }
      if (bin < 0) bin = 0;
      sh_k = kk - (c - (int)hist[bin]);   // how many == T to keep (ties)
      sh_prefix = pref | ((unsigned)bin << shift);
    }
    __syncthreads();
  }

  const unsigned T = sh_prefix;  // bit pattern of KEEP-th largest
  const int keq = sh_k;
  float vals[3];
  bool kp[3];
  float local = 0.f;
  int cnt = 0;
  for (int j = tid; j < NTOK; j += 256, ++cnt) {
    float fv = row[j];
    unsigned ub = __float_as_uint(fv);
    bool k1 = (ub > T);
    if (ub == T) {  // tie at threshold: keep lowest indices first (jax top_k)
      int r = 0;
      for (int jj = 0; jj < j; ++jj)
        if (__float_as_uint(row[jj]) == T) ++r;
      k1 = (r < keq);
    }
    if (j == 0) k1 = true;  // CLS column always kept
    vals[cnt] = fv;
    kp[cnt] = k1;
    if (k1) local += fv;
  }
  for (int off = 32; off; off >>= 1) local += __shfl_down(local, off, 64);
  if ((tid & 63) == 0) sred[tid >> 6] = local;
  __syncthreads();
  if (tid == 0) sh_inv = 1.f / (sred[0] + sred[1] + sred[2] + sred[3] + 1.f);
  __syncthreads();
  const float inv = sh_inv;
  float* Arow = Amat + ((size_t)(b * NTOK + i)) * NTOK;
  cnt = 0;
  for (int j = tid; j < NTOK; j += 256, ++cnt) {
    float a = (kp[cnt] ? vals[cnt] : 0.f) + ((j == i) ? 1.f : 0.f);
    Arow[j] = a * inv;
  }
}

// ---------------------------------------------------------------------------
// vmul: v_out[j] = sum_i v_in[i] * A[b][i][j]   (left vector-matrix product)
// grid = BATCH*3 blocks (3 chunks of 256 j's). Skips uniform-zero v entries.
// ---------------------------------------------------------------------------
__global__ __launch_bounds__(256) void vmul_kernel(const float* __restrict__ Amat,
                                                   const float* __restrict__ vin,
                                                   float* __restrict__ vout) {
  const int b = blockIdx.x / 3;
  const int ch = blockIdx.x % 3;
  const int j = ch * 256 + threadIdx.x;
  __shared__ float vsh[NTOK];
  for (int t = threadIdx.x; t < NTOK; t += 256) vsh[t] = vin[b * NTOK + t];
  __syncthreads();
  if (j < NTOK) {
    float acc = 0.f;
    const float* Ab = Amat + (size_t)b * NTOK * NTOK + j;
    for (int i = 0; i < NTOK; ++i) {
      float vi = vsh[i];             // uniform across block
      if (vi != 0.f) acc += vi * Ab[(size_t)i * NTOK];
    }
    vout[b * NTOK + j] = acc;
  }
}

// ---------------------------------------------------------------------------
// topk: per-batch top-57 of scores (v_final[1..576]), descending, ties to
// lower index (key = valbits<<32 | (0xFFFFFFFF - n); values are >= 0).
// ---------------------------------------------------------------------------
__global__ __launch_bounds__(256) void topk_kernel(const float* __restrict__ vfin,
                                                   int* __restrict__ sel,
                                                   int* __restrict__ selpos,
                                                   int* __restrict__ unionmask,
                                                   int* __restrict__ rowidx) {
  const int b = blockIdx.x;
  const int tid = threadIdx.x;
  __shared__ unsigned long long key[NTOK];
  __shared__ unsigned long long red[4];
  for (int n = tid; n < NTOK; n += 256) {
    float v = vfin[b * NTOK + n];
    unsigned ub = __float_as_uint(v);
    key[n] = (n >= 1)
                 ? ((((unsigned long long)ub) << 32) |
                    (unsigned long long)(0xFFFFFFFFu - (unsigned)n))
                 : 0ULL;  // exclude CLS (sentinel below any real key)
  }
  __syncthreads();
  for (int s = 0; s < SSEL; ++s) {
    unsigned long long mk = 0ULL;
    for (int n = tid; n < NTOK; n += 256) {
      unsigned long long k2 = key[n];
      if (k2 > mk) mk = k2;
    }
    for (int off = 32; off; off >>= 1) {
      unsigned long long o = __shfl_down(mk, off, 64);
      if (o > mk) mk = o;
    }
    if ((tid & 63) == 0) red[tid >> 6] = mk;
    __syncthreads();
    if (tid == 0) {
      unsigned long long m = red[0];
      if (red[1] > m) m = red[1];
      if (red[2] > m) m = red[2];
      if (red[3] > m) m = red[3];
      int n = (int)(0xFFFFFFFFu - (unsigned)(m & 0xFFFFFFFFull));
      sel[b * SSEL + s] = n;
      selpos[b * NTOK + n] = s + 1;
      unionmask[n] = 1;  // racy 1-writes across batches: benign
      rowidx[b * SSEL + s] = b * NTOK + n;
      key[n] = 0ULL;
    }
    __syncthreads();
  }
}

// ---------------------------------------------------------------------------
// gemm_nt: C[m,n] = sum_c A[m,c]*W[n,c] + bias[n]; K = CDIM = 768.
// 64x64 tile, BK=16, 256 threads, 4x4 microtile. Optional row gather via
// rowidx (used for the selected-query projection).
// ---------------------------------------------------------------------------
__global__ __launch_bounds__(256) void gemm_nt(const float* __restrict__ A,
                                               const float* __restrict__ W,
                                               const float* __restrict__ bias,
                                               float* __restrict__ C, int M,
                                               const int* __restrict__ rowidx) {
  __shared__ float As[16][68];
  __shared__ float Bs[16][68];
  const int tid = threadIdx.x;
  const int lm = tid >> 2;         // 0..63: row within tile for staging
  const int lk = (tid & 3) << 2;   // 0,4,8,12: k offset for float4
  const int mrow = blockIdx.x * 64 + lm;
  const bool mv = (mrow < M);
  const float* Abase = A;  // dummy; only dereferenced when mv
  if (mv) {
    int ridx = rowidx ? rowidx[mrow] : mrow;
    Abase = A + (size_t)ridx * CDIM;
  }
  const int nrow = blockIdx.y * 64 + lm;
  const float* Wbase = W + (size_t)nrow * CDIM;

  const int m0 = (tid & 15) << 2;
  const int n0 = (tid >> 4) << 2;
  float acc[4][4] = {{0.f}};

  for (int k0 = 0; k0 < CDIM; k0 += 16) {
    float4 av = mv ? *(const float4*)(Abase + k0 + lk) : make_float4(0.f, 0.f, 0.f, 0.f);
    float4 bv = *(const float4*)(Wbase + k0 + lk);
    __syncthreads();
    As[lk + 0][lm] = av.x; As[lk + 1][lm] = av.y;
    As[lk + 2][lm] = av.z; As[lk + 3][lm] = av.w;
    Bs[lk + 0][lm] = bv.x; Bs[lk + 1][lm] = bv.y;
    Bs[lk + 2][lm] = bv.z; Bs[lk + 3][lm] = bv.w;
    __syncthreads();
#pragma unroll
    for (int k = 0; k < 16; ++k) {
      float a0 = As[k][m0 + 0], a1 = As[k][m0 + 1], a2 = As[k][m0 + 2], a3 = As[k][m0 + 3];
      float b0 = Bs[k][n0 + 0], b1 = Bs[k][n0 + 1], b2 = Bs[k][n0 + 2], b3 = Bs[k][n0 + 3];
      acc[0][0] += a0 * b0; acc[0][1] += a0 * b1; acc[0][2] += a0 * b2; acc[0][3] += a0 * b3;
      acc[1][0] += a1 * b0; acc[1][1] += a1 * b1; acc[1][2] += a1 * b2; acc[1][3] += a1 * b3;
      acc[2][0] += a2 * b0; acc[2][1] += a2 * b1; acc[2][2] += a2 * b2; acc[2][3] += a2 * b3;
      acc[3][0] += a3 * b0; acc[3][1] += a3 * b1; acc[3][2] += a3 * b2; acc[3][3] += a3 * b3;
    }
  }
  const int cmBase = blockIdx.x * 64 + m0;
  const int cnBase = blockIdx.y * 64 + n0;
#pragma unroll
  for (int ii = 0; ii < 4; ++ii) {
    int cm = cmBase + ii;
    if (cm < M) {
      float* crow = C + (size_t)cm * CDIM + cnBase;
#pragma unroll
      for (int jj = 0; jj < 4; ++jj) crow[jj] = acc[ii][jj] + bias[cnBase + jj];
    }
  }
}

// ---------------------------------------------------------------------------
// attention: block per (b, h, chunk-of-8-queries). S=QK^T*0.125, row softmax
// (attn_w streamed to d_out), O = P@V into obuf (head-merged layout).
// ---------------------------------------------------------------------------
__global__ __launch_bounds__(256) void attn_kernel(const float* __restrict__ qbuf,
                                                   const float* __restrict__ kbuf,
                                                   const float* __restrict__ vbuf,
                                                   float* __restrict__ attnw,
                                                   float* __restrict__ obuf) {
  const int bx = blockIdx.x;
  const int b = bx / (HEADS * 8);
  const int rem = bx % (HEADS * 8);
  const int h = rem / 8;
  const int ch = rem % 8;
  const int s0 = ch * 8;
  int ns = SSEL - s0;
  if (ns > 8) ns = 8;
  const int tid = threadIdx.x;
  __shared__ float Q[8][64];
  __shared__ float P[8][580];
  __shared__ float sred[4];
  __shared__ float sbc;

  for (int t = tid; t < 512; t += 256) {
    int s = t >> 6, d = t & 63;
    Q[s][d] = (s < ns) ? qbuf[((size_t)(b * SSEL + s0 + s)) * CDIM + h * 64 + d] : 0.f;
  }
  __syncthreads();

  for (int e = tid; e < ns * NTOK; e += 256) {
    int s = e / NTOK, n = e % NTOK;
    const float* kr = kbuf + ((size_t)(b * NTOK + n)) * CDIM + h * 64;
    float acc = 0.f;
#pragma unroll
    for (int d = 0; d < 64; ++d) acc += Q[s][d] * kr[d];
    P[s][n] = acc * 0.125f;  // D^-0.5, D=64
  }
  __syncthreads();

  for (int s = 0; s < ns; ++s) {
    float m = -1e30f;
    for (int n = tid; n < NTOK; n += 256) m = fmaxf(m, P[s][n]);
    for (int off = 32; off; off >>= 1) m = fmaxf(m, __shfl_down(m, off, 64));
    if ((tid & 63) == 0) sred[tid >> 6] = m;
    __syncthreads();
    if (tid == 0) sbc = fmaxf(fmaxf(sred[0], sred[1]), fmaxf(sred[2], sred[3]));
    __syncthreads();
    m = sbc;
    float lsum = 0.f;
    for (int n = tid; n < NTOK; n += 256) {
      float e_ = expf(P[s][n] - m);
      P[s][n] = e_;
      lsum += e_;
    }
    for (int off = 32; off; off >>= 1) lsum += __shfl_down(lsum, off, 64);
    if ((tid & 63) == 0) sred[tid >> 6] = lsum;
    __syncthreads();
    if (tid == 0) sbc = 1.f / (sred[0] + sred[1] + sred[2] + sred[3]);
    __syncthreads();
    float inv = sbc;
    float* aw = attnw + ((size_t)((b * HEADS + h) * SSEL + s0 + s)) * NTOK;
    for (int n = tid; n < NTOK; n += 256) {
      float p = P[s][n] * inv;
      P[s][n] = p;
      aw[n] = p;
    }
    __syncthreads();
  }

  for (int t = tid; t < ns * 64; t += 256) {
    int s = t >> 6, d = t & 63;
    float acc = 0.f;
    for (int n = 0; n < NTOK; ++n)
      acc += P[s][n] * vbuf[((size_t)(b * NTOK + n)) * CDIM + h * 64 + d];
    obuf[((size_t)(b * SSEL + s0 + s)) * CDIM + h * 64 + d] = acc;
  }
}

// ---------------------------------------------------------------------------
// scatter: output[b,0]=x; selected -> o2 row; union-selected-elsewhere -> 0;
// otherwise -> x.
// ---------------------------------------------------------------------------
__global__ void scatter_kernel(const float* __restrict__ x, const float* __restrict__ o2,
                               const int* __restrict__ selpos,
                               const int* __restrict__ unionmask,
                               float* __restrict__ out) {
  int idx = blockIdx.x * 256 + threadIdx.x;
  const int total = BATCH * NTOK * CDIM;
  if (idx >= total) return;
  int b = idx / (NTOK * CDIM);
  int r = idx % (NTOK * CDIM);
  int n = r / CDIM;
  int c = r % CDIM;
  float val;
  if (n == 0) {
    val = x[idx];
  } else {
    int sp = selpos[b * NTOK + n];
    if (sp > 0)
      val = o2[((size_t)(b * SSEL + sp - 1)) * CDIM + c];
    else if (unionmask[n])
      val = 0.f;
    else
      val = x[idx];
  }
  out[idx] = val;
}

// ---------------------------------------------------------------------------
extern "C" void kernel_launch(void* const* d_in, const int* in_sizes, int n_in,
                              void* d_out, int out_size, void* d_ws, size_t ws_size,
                              hipStream_t stream) {
  const float* x = (const float*)d_in[0];
  const float* ah = (const float*)d_in[1];
  const float* Wq = (const float*)d_in[2];
  const float* bq = (const float*)d_in[3];
  const float* Wk = (const float*)d_in[4];
  const float* bk = (const float*)d_in[5];
  const float* Wv = (const float*)d_in[6];
  const float* bv = (const float*)d_in[7];
  const float* Wo = (const float*)d_in[8];
  const float* bo = (const float*)d_in[9];
  float* out = (float*)d_out;
  float* attnw = out + (size_t)BATCH * NTOK * CDIM;

  char* w = (char*)d_ws;
  auto carve = [&](size_t bytes) -> char* {
    char* p = w;
    w += (bytes + 255) & ~(size_t)255;
    return p;
  };
  float* Abuf = (float*)carve((size_t)BATCH * NTOK * NTOK * 4);   // 5.3 MB
  float* v0 = (float*)carve((size_t)BATCH * NTOK * 4);
  float* v1 = (float*)carve((size_t)BATCH * NTOK * 4);
  float* kbuf = (float*)carve((size_t)MROWS * CDIM * 4);          // 7.1 MB
  float* vbuf = (float*)carve((size_t)MROWS * CDIM * 4);          // 7.1 MB
  float* qbuf = (float*)carve((size_t)BATCH * SSEL * CDIM * 4);
  float* obuf = (float*)carve((size_t)BATCH * SSEL * CDIM * 4);
  float* o2buf = (float*)carve((size_t)BATCH * SSEL * CDIM * 4);
  int* selbuf = (int*)carve((size_t)BATCH * SSEL * 4);
  int* selpos = (int*)carve((size_t)BATCH * NTOK * 4);
  int* unionm = (int*)carve((size_t)NTOK * 4);
  int* rowidx = (int*)carve((size_t)BATCH * SSEL * 4);

  init_kernel<<<(BATCH * NTOK + 255) / 256, 256, 0, stream>>>(v0, selpos, unionm);

  // rollout as left-vector products: scores = e0^T * A11 * A10 * ... * A0
  for (int t = 0; t < LAYERS; ++t) {
    int l = LAYERS - 1 - t;
    fuse_select<<<BATCH * NTOK, 256, 0, stream>>>(
        ah + (size_t)l * BATCH * HEADS * NTOK * NTOK, Abuf);
    const float* vin = (t % 2 == 0) ? v0 : v1;
    float* vout = (t % 2 == 0) ? v1 : v0;
    vmul_kernel<<<BATCH * 3, 256, 0, stream>>>(Abuf, vin, vout);
  }
  // 12 steps -> final vector lands in v0
  topk_kernel<<<BATCH, 256, 0, stream>>>(v0, selbuf, selpos, unionm, rowidx);

  dim3 gKV((MROWS + 63) / 64, CDIM / 64);
  gemm_nt<<<gKV, 256, 0, stream>>>(x, Wk, bk, kbuf, MROWS, nullptr);
  gemm_nt<<<gKV, 256, 0, stream>>>(x, Wv, bv, vbuf, MROWS, nullptr);
  dim3 gQ((BATCH * SSEL + 63) / 64, CDIM / 64);
  gemm_nt<<<gQ, 256, 0, stream>>>(x, Wq, bq, qbuf, BATCH * SSEL, rowidx);
  attn_kernel<<<BATCH * HEADS * 8, 256, 0, stream>>>(qbuf, kbuf, vbuf, attnw, obuf);
  gemm_nt<<<gQ, 256, 0, stream>>>(obuf, Wo, bo, o2buf, BATCH * SSEL, nullptr);
  scatter_kernel<<<(BATCH * NTOK * CDIM + 255) / 256, 256, 0, stream>>>(
      x, o2buf, selpos, unionm, out);
}

// Round 2
// 1716.408 us; speedup vs baseline: 2.6538x; 2.6538x over previous
//
#include <hip/hip_runtime.h>

#define NTOK 577
#define BATCH 4
#define HEADS 12
#define LAYERS 12
#define CDIM 768
#define SSEL 57
#define KEEP 58
#define MROWS (BATCH * NTOK)  // 2308
#define NR 10                 // ceil(577/64) register slots per lane
#define IC 16                 // i-chunks for vmul partials

// ---------------------------------------------------------------------------
// init: zero selpos/union masks
// ---------------------------------------------------------------------------
__global__ void init_kernel(int* selpos, int* unionmask) {
  int i = blockIdx.x * 256 + threadIdx.x;
  if (i < BATCH * NTOK) selpos[i] = 0;
  if (i < NTOK) unionmask[i] = 0;
}

// ---------------------------------------------------------------------------
// fuse_all: ONE wave per (layer, b, row i); all 12 layers in one launch.
// Head-fusion mean -> exact 58th-largest threshold via 31-step binary search
// on positive-float bit patterns (registers + shuffles only; no LDS/atomics).
// Writes normalized rollout row A[l][b][i][j] = (kept + diag) / (sum+1).
// ---------------------------------------------------------------------------
__global__ __launch_bounds__(256) void fuse_all(const float* __restrict__ ah,
                                                float* __restrict__ Abuf) {
  const int w = blockIdx.x * 4 + (threadIdx.x >> 6);  // wave id, < 27696
  const int lane = threadIdx.x & 63;
  const int l = w / (BATCH * NTOK);
  const int rr = w % (BATCH * NTOK);
  const int b = rr / NTOK;
  const int i = rr % NTOK;
  const float* base =
      ah + ((((size_t)l * BATCH + b) * HEADS) * NTOK + i) * NTOK;

  float val[NR];
  unsigned ub[NR];
#pragma unroll
  for (int r = 0; r < NR; ++r) {
    const int j = lane + 64 * r;
    float s = 0.f;
    if (j < NTOK) {
#pragma unroll
      for (int h = 0; h < HEADS; ++h)
        s += __builtin_nontemporal_load(&base[(size_t)h * NTOK * NTOK + j]);
      s = s / 12.f;  // same op order as the verified round-1 version
    }
    val[r] = s;
    ub[r] = (j < NTOK) ? __float_as_uint(s) : 0u;  // values > 0 -> uint order
  }

  // binary search: tau = bit pattern of KEEP-th largest
  unsigned tau = 0u;
  for (int bit = 30; bit >= 0; --bit) {
    const unsigned cand = tau | (1u << bit);
    int c = 0;
#pragma unroll
    for (int r = 0; r < NR; ++r) c += ((ub[r] >> bit) >= (cand >> bit));
#pragma unroll
    for (int off = 1; off < 64; off <<= 1) c += __shfl_xor(c, off, 64);
    if (c >= KEEP) tau = cand;
  }

  int cgt = 0;
#pragma unroll
  for (int r = 0; r < NR; ++r) cgt += (ub[r] > tau);
#pragma unroll
  for (int off = 1; off < 64; off <<= 1) cgt += __shfl_xor(cgt, off, 64);
  const int keq = KEEP - cgt;  // how many tau-equal elements to keep

  unsigned long long em[NR];
#pragma unroll
  for (int r = 0; r < NR; ++r) em[r] = __ballot(ub[r] == tau);
  const unsigned long long ltm = (1ull << lane) - 1ull;

  bool kp[NR];
  int pre = 0;  // equal-count in slots r' < r (wave-uniform)
  float ksum = 0.f;
#pragma unroll
  for (int r = 0; r < NR; ++r) {
    const int j = lane + 64 * r;
    bool k1 = (ub[r] > tau);
    if (ub[r] == tau) {  // ties: lowest j first (jax top_k semantics)
      const int rank = pre + __popcll(em[r] & ltm);
      k1 = (rank < keq);
    }
    if (j == 0) k1 = true;  // CLS column always kept
    kp[r] = k1;
    if (k1) ksum += val[r];
    pre += __popcll(em[r]);
  }
#pragma unroll
  for (int off = 1; off < 64; off <<= 1) ksum += __shfl_xor(ksum, off, 64);
  const float inv = 1.f / (ksum + 1.f);  // 0.5 residual factors cancel

  float* Arow = Abuf + (((size_t)(l * BATCH + b) * NTOK) + i) * NTOK;
#pragma unroll
  for (int r = 0; r < NR; ++r) {
    const int j = lane + 64 * r;
    if (j < NTOK)
      Arow[j] = ((kp[r] ? val[r] : 0.f) + ((j == i) ? 1.f : 0.f)) * inv;
  }
}

// ---------------------------------------------------------------------------
// vmul_part: partial left vector-matrix product for one layer.
//   vin[i] folded from previous layer's IC partials (fixed order, det.);
//   pin == nullptr -> vin = e0. grid (BATCH*3, IC). Unconditional FMA so
//   loads pipeline.
// ---------------------------------------------------------------------------
__global__ __launch_bounds__(256) void vmul_part(const float* __restrict__ Al,
                                                 const float* __restrict__ pin,
                                                 float* __restrict__ pout) {
  const int b = blockIdx.x / 3;
  const int jc = blockIdx.x % 3;
  const int ic = blockIdx.y;
  const int tid = threadIdx.x;
  __shared__ float vsh[NTOK];
  for (int t = tid; t < NTOK; t += 256) {
    float s;
    if (pin) {
      s = 0.f;
#pragma unroll
      for (int c = 0; c < IC; ++c) s += pin[c * MROWS + b * NTOK + t];
    } else {
      s = (t == 0) ? 1.f : 0.f;
    }
    vsh[t] = s;
  }
  __syncthreads();
  const int j = jc * 256 + tid;
  if (j >= NTOK) return;
  const int i0 = ic * 36;
  const int i1 = (ic == IC - 1) ? NTOK : (i0 + 36);
  const float* Ab = Al + (size_t)b * NTOK * NTOK + j;
  float acc = 0.f;
  for (int i = i0; i < i1; ++i) acc += vsh[i] * Ab[(size_t)i * NTOK];
  pout[ic * MROWS + b * NTOK + j] = acc;
}

// ---------------------------------------------------------------------------
// topk: one wave per batch. Folds final partials, selects top-57 of
// scores[1..576] descending with lowest-index ties; register keys, no LDS.
// ---------------------------------------------------------------------------
__global__ __launch_bounds__(64) void topk_kernel(const float* __restrict__ pin,
                                                  int* __restrict__ sel,
                                                  int* __restrict__ selpos,
                                                  int* __restrict__ unionmask,
                                                  int* __restrict__ rowidx) {
  const int b = blockIdx.x;
  const int lane = threadIdx.x;
  unsigned long long key[NR];
#pragma unroll
  for (int r = 0; r < NR; ++r) {
    const int n = lane + 64 * r;
    unsigned long long k2 = 0ull;
    if (n >= 1 && n < NTOK) {
      float s = 0.f;
#pragma unroll
      for (int c = 0; c < IC; ++c) s += pin[c * MROWS + b * NTOK + n];
      k2 = (((unsigned long long)__float_as_uint(s)) << 32) |
           (unsigned long long)(0xFFFFFFFFu - (unsigned)n);
    }
    key[r] = k2;
  }
  for (int s = 0; s < SSEL; ++s) {
    unsigned long long mk = 0ull;
#pragma unroll
    for (int r = 0; r < NR; ++r) mk = (key[r] > mk) ? key[r] : mk;
#pragma unroll
    for (int off = 1; off < 64; off <<= 1) {
      unsigned long long o = __shfl_xor(mk, off, 64);
      if (o > mk) mk = o;
    }
    const int n = (int)(0xFFFFFFFFu - (unsigned)(mk & 0xFFFFFFFFull));
#pragma unroll
    for (int r = 0; r < NR; ++r)
      if (key[r] == mk) key[r] = 0ull;  // unique keys: exactly one owner
    if (lane == 0) {
      sel[b * SSEL + s] = n;
      selpos[b * NTOK + n] = s + 1;
      unionmask[n] = 1;
      rowidx[b * SSEL + s] = b * NTOK + n;
    }
  }
}

// ---------------------------------------------------------------------------
// gemm_nt: C[m,n] = sum_c A[m,c]*W[n,c] + bias[n]; K = CDIM = 768.
// 64x64 tile, BK=16, 256 threads, 4x4 microtile. Optional row gather.
// ---------------------------------------------------------------------------
__global__ __launch_bounds__(256) void gemm_nt(const float* __restrict__ A,
                                               const float* __restrict__ W,
                                               const float* __restrict__ bias,
                                               float* __restrict__ C, int M,
                                               const int* __restrict__ rowidx) {
  __shared__ float As[16][68];
  __shared__ float Bs[16][68];
  const int tid = threadIdx.x;
  const int lm = tid >> 2;
  const int lk = (tid & 3) << 2;
  const int mrow = blockIdx.x * 64 + lm;
  const bool mv = (mrow < M);
  const float* Abase = A;
  if (mv) {
    int ridx = rowidx ? rowidx[mrow] : mrow;
    Abase = A + (size_t)ridx * CDIM;
  }
  const int nrow = blockIdx.y * 64 + lm;
  const float* Wbase = W + (size_t)nrow * CDIM;

  const int m0 = (tid & 15) << 2;
  const int n0 = (tid >> 4) << 2;
  float acc[4][4] = {{0.f}};

  for (int k0 = 0; k0 < CDIM; k0 += 16) {
    float4 av = mv ? *(const float4*)(Abase + k0 + lk) : make_float4(0.f, 0.f, 0.f, 0.f);
    float4 bv = *(const float4*)(Wbase + k0 + lk);
    __syncthreads();
    As[lk + 0][lm] = av.x; As[lk + 1][lm] = av.y;
    As[lk + 2][lm] = av.z; As[lk + 3][lm] = av.w;
    Bs[lk + 0][lm] = bv.x; Bs[lk + 1][lm] = bv.y;
    Bs[lk + 2][lm] = bv.z; Bs[lk + 3][lm] = bv.w;
    __syncthreads();
#pragma unroll
    for (int k = 0; k < 16; ++k) {
      float a0 = As[k][m0 + 0], a1 = As[k][m0 + 1], a2 = As[k][m0 + 2], a3 = As[k][m0 + 3];
      float b0 = Bs[k][n0 + 0], b1 = Bs[k][n0 + 1], b2 = Bs[k][n0 + 2], b3 = Bs[k][n0 + 3];
      acc[0][0] += a0 * b0; acc[0][1] += a0 * b1; acc[0][2] += a0 * b2; acc[0][3] += a0 * b3;
      acc[1][0] += a1 * b0; acc[1][1] += a1 * b1; acc[1][2] += a1 * b2; acc[1][3] += a1 * b3;
      acc[2][0] += a2 * b0; acc[2][1] += a2 * b1; acc[2][2] += a2 * b2; acc[2][3] += a2 * b3;
      acc[3][0] += a3 * b0; acc[3][1] += a3 * b1; acc[3][2] += a3 * b2; acc[3][3] += a3 * b3;
    }
  }
  const int cmBase = blockIdx.x * 64 + m0;
  const int cnBase = blockIdx.y * 64 + n0;
#pragma unroll
  for (int ii = 0; ii < 4; ++ii) {
    int cm = cmBase + ii;
    if (cm < M) {
      float* crow = C + (size_t)cm * CDIM + cnBase;
#pragma unroll
      for (int jj = 0; jj < 4; ++jj) crow[jj] = acc[ii][jj] + bias[cnBase + jj];
    }
  }
}

// ---------------------------------------------------------------------------
// attention: block per (b, h, chunk-of-8-queries). S=QK^T*0.125, row softmax
// (attn_w streamed to d_out), O = P@V into obuf (head-merged layout).
// ---------------------------------------------------------------------------
__global__ __launch_bounds__(256) void attn_kernel(const float* __restrict__ qbuf,
                                                   const float* __restrict__ kbuf,
                                                   const float* __restrict__ vbuf,
                                                   float* __restrict__ attnw,
                                                   float* __restrict__ obuf) {
  const int bx = blockIdx.x;
  const int b = bx / (HEADS * 8);
  const int rem = bx % (HEADS * 8);
  const int h = rem / 8;
  const int ch = rem % 8;
  const int s0 = ch * 8;
  int ns = SSEL - s0;
  if (ns > 8) ns = 8;
  const int tid = threadIdx.x;
  __shared__ float Q[8][64];
  __shared__ float P[8][580];
  __shared__ float sred[4];
  __shared__ float sbc;

  for (int t = tid; t < 512; t += 256) {
    int s = t >> 6, d = t & 63;
    Q[s][d] = (s < ns) ? qbuf[((size_t)(b * SSEL + s0 + s)) * CDIM + h * 64 + d] : 0.f;
  }
  __syncthreads();

  for (int e = tid; e < ns * NTOK; e += 256) {
    int s = e / NTOK, n = e % NTOK;
    const float* kr = kbuf + ((size_t)(b * NTOK + n)) * CDIM + h * 64;
    float acc = 0.f;
#pragma unroll
    for (int d = 0; d < 64; ++d) acc += Q[s][d] * kr[d];
    P[s][n] = acc * 0.125f;
  }
  __syncthreads();

  for (int s = 0; s < ns; ++s) {
    float m = -1e30f;
    for (int n = tid; n < NTOK; n += 256) m = fmaxf(m, P[s][n]);
    for (int off = 32; off; off >>= 1) m = fmaxf(m, __shfl_down(m, off, 64));
    if ((tid & 63) == 0) sred[tid >> 6] = m;
    __syncthreads();
    if (tid == 0) sbc = fmaxf(fmaxf(sred[0], sred[1]), fmaxf(sred[2], sred[3]));
    __syncthreads();
    m = sbc;
    float lsum = 0.f;
    for (int n = tid; n < NTOK; n += 256) {
      float e_ = expf(P[s][n] - m);
      P[s][n] = e_;
      lsum += e_;
    }
    for (int off = 32; off; off >>= 1) lsum += __shfl_down(lsum, off, 64);
    if ((tid & 63) == 0) sred[tid >> 6] = lsum;
    __syncthreads();
    if (tid == 0) sbc = 1.f / (sred[0] + sred[1] + sred[2] + sred[3]);
    __syncthreads();
    float inv = sbc;
    float* aw = attnw + ((size_t)((b * HEADS + h) * SSEL + s0 + s)) * NTOK;
    for (int n = tid; n < NTOK; n += 256) {
      float p = P[s][n] * inv;
      P[s][n] = p;
      aw[n] = p;
    }
    __syncthreads();
  }

  for (int t = tid; t < ns * 64; t += 256) {
    int s = t >> 6, d = t & 63;
    float acc = 0.f;
    for (int n = 0; n < NTOK; ++n)
      acc += P[s][n] * vbuf[((size_t)(b * NTOK + n)) * CDIM + h * 64 + d];
    obuf[((size_t)(b * SSEL + s0 + s)) * CDIM + h * 64 + d] = acc;
  }
}

// ---------------------------------------------------------------------------
// scatter: output[b,0]=x; selected -> o2 row; union-selected-elsewhere -> 0;
// otherwise -> x.
// ---------------------------------------------------------------------------
__global__ void scatter_kernel(const float* __restrict__ x, const float* __restrict__ o2,
                               const int* __restrict__ selpos,
                               const int* __restrict__ unionmask,
                               float* __restrict__ out) {
  int idx = blockIdx.x * 256 + threadIdx.x;
  const int total = BATCH * NTOK * CDIM;
  if (idx >= total) return;
  int b = idx / (NTOK * CDIM);
  int r = idx % (NTOK * CDIM);
  int n = r / CDIM;
  int c = r % CDIM;
  float val;
  if (n == 0) {
    val = x[idx];
  } else {
    int sp = selpos[b * NTOK + n];
    if (sp > 0)
      val = o2[((size_t)(b * SSEL + sp - 1)) * CDIM + c];
    else if (unionmask[n])
      val = 0.f;
    else
      val = x[idx];
  }
  out[idx] = val;
}

// ---------------------------------------------------------------------------
extern "C" void kernel_launch(void* const* d_in, const int* in_sizes, int n_in,
                              void* d_out, int out_size, void* d_ws, size_t ws_size,
                              hipStream_t stream) {
  const float* x = (const float*)d_in[0];
  const float* ah = (const float*)d_in[1];
  const float* Wq = (const float*)d_in[2];
  const float* bq = (const float*)d_in[3];
  const float* Wk = (const float*)d_in[4];
  const float* bk = (const float*)d_in[5];
  const float* Wv = (const float*)d_in[6];
  const float* bv = (const float*)d_in[7];
  const float* Wo = (const float*)d_in[8];
  const float* bo = (const float*)d_in[9];
  float* out = (float*)d_out;
  float* attnw = out + (size_t)BATCH * NTOK * CDIM;

  char* w = (char*)d_ws;
  auto carve = [&](size_t bytes) -> char* {
    char* p = w;
    w += (bytes + 255) & ~(size_t)255;
    return p;
  };
  float* Abuf = (float*)carve((size_t)LAYERS * BATCH * NTOK * NTOK * 4);  // 64 MB
  float* partA = (float*)carve((size_t)IC * MROWS * 4);
  float* partB = (float*)carve((size_t)IC * MROWS * 4);
  float* kbuf = (float*)carve((size_t)MROWS * CDIM * 4);
  float* vbuf = (float*)carve((size_t)MROWS * CDIM * 4);
  float* qbuf = (float*)carve((size_t)BATCH * SSEL * CDIM * 4);
  float* obuf = (float*)carve((size_t)BATCH * SSEL * CDIM * 4);
  float* o2buf = (float*)carve((size_t)BATCH * SSEL * CDIM * 4);
  int* selbuf = (int*)carve((size_t)BATCH * SSEL * 4);
  int* selpos = (int*)carve((size_t)BATCH * NTOK * 4);
  int* unionm = (int*)carve((size_t)NTOK * 4);
  int* rowidx = (int*)carve((size_t)BATCH * SSEL * 4);

  init_kernel<<<(BATCH * NTOK + 255) / 256, 256, 0, stream>>>(selpos, unionm);

  // all 12 rollout matrices in one launch (independent of each other)
  fuse_all<<<(LAYERS * MROWS) / 4, 256, 0, stream>>>(ah, Abuf);

  // left-vector chain: scores = e0^T * A11 * A10 * ... * A0
  const float* pin = nullptr;
  float* pout = partA;
  for (int t = 0; t < LAYERS; ++t) {
    int l = LAYERS - 1 - t;
    vmul_part<<<dim3(BATCH * 3, IC), 256, 0, stream>>>(
        Abuf + (size_t)l * BATCH * NTOK * NTOK, pin, pout);
    pin = pout;
    pout = (pout == partA) ? partB : partA;
  }
  topk_kernel<<<BATCH, 64, 0, stream>>>(pin, selbuf, selpos, unionm, rowidx);

  dim3 gKV((MROWS + 63) / 64, CDIM / 64);
  gemm_nt<<<gKV, 256, 0, stream>>>(x, Wk, bk, kbuf, MROWS, nullptr);
  gemm_nt<<<gKV, 256, 0, stream>>>(x, Wv, bv, vbuf, MROWS, nullptr);
  dim3 gQ((BATCH * SSEL + 63) / 64, CDIM / 64);
  gemm_nt<<<gQ, 256, 0, stream>>>(x, Wq, bq, qbuf, BATCH * SSEL, rowidx);
  attn_kernel<<<BATCH * HEADS * 8, 256, 0, stream>>>(qbuf, kbuf, vbuf, attnw, obuf);
  gemm_nt<<<gQ, 256, 0, stream>>>(obuf, Wo, bo, o2buf, BATCH * SSEL, nullptr);
  scatter_kernel<<<(BATCH * NTOK * CDIM + 255) / 256, 256, 0, stream>>>(
      x, o2buf, selpos, unionm, out);
}